// Round 8
// baseline (216.435 us; speedup 1.0000x reference)
//
#include <hip/hip_runtime.h>
#include <hip/hip_bf16.h>

// Problem dims (hard-coded): B=4, C=256, F=16, H=32, W=32 (fp32 in/out)
#define CC 256
#define FF 16
#define PP 1024
#define BB 4
#define NN 64   // B*F

typedef __bf16 bf16x8 __attribute__((ext_vector_type(8)));
typedef float  f32x4  __attribute__((ext_vector_type(4)));

// async 16B global -> LDS (per-lane global addr; LDS dest = wave-uniform base + lane*16)
__device__ __forceinline__ void async16(const __hip_bfloat16* g, char* l) {
    __builtin_amdgcn_global_load_lds(
        (const __attribute__((address_space(1))) unsigned int*)g,
        (__attribute__((address_space(3))) unsigned int*)l, 16, 0, 0);
}

__device__ __forceinline__ float bf2f(unsigned short u) {
    union { unsigned i; float f; } v; v.i = ((unsigned)u) << 16; return v.f;
}

// ---------------------------------------------------------------------------
// wconv_kernel: Wb[proj][d][c] (bf16) from wq/wk/wv (fp32).  64 blocks.
// ---------------------------------------------------------------------------
__global__ __launch_bounds__(256) void wconv_kernel(
    const float* __restrict__ wq, const float* __restrict__ wk,
    const float* __restrict__ wv, __hip_bfloat16* __restrict__ Wb)
{
    const int idx = (blockIdx.x * 256 + threadIdx.x) * 4;
    #pragma unroll
    for (int proj = 0; proj < 3; ++proj) {
        const float* src = proj == 0 ? wq : (proj == 1 ? wk : wv);
        __hip_bfloat16* dst = Wb + (size_t)proj * CC * CC;
        const float4 v = *(const float4*)(src + idx);
        __hip_bfloat162 h0, h1;
        h0.x = __float2bfloat16(v.x); h0.y = __float2bfloat16(v.y);
        h1.x = __float2bfloat16(v.z); h1.y = __float2bfloat16(v.w);
        *(__hip_bfloat162*)(dst + idx)     = h0;
        *(__hip_bfloat162*)(dst + idx + 2) = h1;
    }
}

// ---------------------------------------------------------------------------
// qkv_fused: per (n,proj): Y[d][p] = sum_c W[d][c]*X[c][p] + bias[d]
// 128d x 128p tile, BK=64.  The xt transpose pass is FUSED: per K-step the
// x-slice [64c][128p] is staged fp32 into padded LDS T (pitch 66 f32,
// b64-aligned writes; reads 2-lanes/bank = conflict-free), and each MFMA
// B-fragment is built from 8 ds_read_b32 along c + scalar bf16 casts
// (compiler fuses to v_cvt_pk_bf16_f32).  A (weights, bf16) staged via
// global_load_lds with the proven XOR granule swizzle.  Epilogue bounces
// acc through a per-wave padded LDS tile (stride 144B) for coalesced 16B
// stores.  ALL outputs use the [b][d][f][p] layout.
// ---------------------------------------------------------------------------
__global__ __launch_bounds__(256) void qkv_fused(
    const __hip_bfloat16* __restrict__ Wb, const float* __restrict__ x,
    const float* __restrict__ bq, const float* __restrict__ bk,
    const float* __restrict__ bv,
    __hip_bfloat16* __restrict__ Qw, __hip_bfloat16* __restrict__ Kw,
    __hip_bfloat16* __restrict__ Vw)
{
    __shared__ char lds[36864];   // A: 16KB @0 | T: 64 x 66 f32 @16384 (17.3KB)
                                  // epilogue bounce reuses 0..36K (4 x 9216)

    const int p0 = blockIdx.x * 128, d0 = blockIdx.y * 128;
    const int z = blockIdx.z, proj = z % 3, n = z / 3;
    const int t = threadIdx.x, w = t >> 6, lane = t & 63;
    const int wd = (w >> 1) * 64, wp = (w & 1) * 64;
    const int q = lane >> 4, m16 = lane & 15;

    const __hip_bfloat16* Abase = Wb + (size_t)proj * CC * CC + (size_t)d0 * CC;
    const float* Xbase = x + (size_t)n * CC * PP + p0;
    float* T = (float*)(lds + 16384);            // [64][66] f32

    f32x4 acc[4][4];
    #pragma unroll
    for (int i = 0; i < 4; ++i)
        #pragma unroll
        for (int j = 0; j < 4; ++j)
            acc[i][j] = (f32x4){0.f, 0.f, 0.f, 0.f};

    for (int c0 = 0; c0 < CC; c0 += 64) {
        // ---- stage A (bf16, async16, XOR granule swizzle): 16KB ----
        #pragma unroll
        for (int k = 0; k < 4; ++k) {
            const int s = t + 256 * k;
            const int row = s >> 3;
            const int gc = (s & 7) ^ (row & 7);
            async16(Abase + (size_t)row * CC + c0 + gc * 8, lds + s * 16);
        }
        // ---- stage T (fp32 x-slice, untransposed): 64 rows x 128 f32 ----
        // 8 sweeps of 4KB; thread covers (row r = u>>5, quad qd = u&31).
        #pragma unroll
        for (int k = 0; k < 8; ++k) {
            const int u = t + 256 * k;
            const int r = u >> 5, qd = u & 31;
            const float4 v = *(const float4*)(Xbase + (size_t)(c0 + r) * PP + qd * 4);
            float* dstp = T + r * 66 + qd * 4;   // byte off mod 8 == 0
            *(float2*)(dstp)     = make_float2(v.x, v.y);
            *(float2*)(dstp + 2) = make_float2(v.z, v.w);
        }
        __syncthreads();   // drains vmcnt (A) + lgkmcnt (T writes)

        #pragma unroll
        for (int kk = 0; kk < 2; ++kk) {
            bf16x8 a[4], b[4];
            #pragma unroll
            for (int i = 0; i < 4; ++i) {
                const int row = wd + i * 16 + m16;
                const int col = (4 * kk + q) ^ (row & 7);
                a[i] = *(const bf16x8*)(lds + row * 128 + col * 16);
            }
            #pragma unroll
            for (int j = 0; j < 4; ++j) {
                const int p_l = wp + j * 16 + m16;
                const float* Tc = T + (kk * 32 + q * 8) * 66 + p_l;
                #pragma unroll
                for (int e = 0; e < 8; ++e)
                    b[j][e] = (__bf16)Tc[e * 66];
            }
            #pragma unroll
            for (int i = 0; i < 4; ++i)
                #pragma unroll
                for (int j = 0; j < 4; ++j)
                    acc[i][j] = __builtin_amdgcn_mfma_f32_16x16x32_bf16(a[i], b[j], acc[i][j], 0, 0, 0);
        }
        __syncthreads();   // all reads done before restage / bounce reuse
    }

    // ---- epilogue: bounce through per-wave LDS tile, emit coalesced stores ----
    char* wb = lds + w * 9216;             // 64 rows x 144 B
    const int dl2 = lane >> 3, pl2 = lane & 7;

    const float* bias = (proj == 0) ? bq : ((proj == 1) ? bk : bv);
    #pragma unroll
    for (int i = 0; i < 4; ++i)
        #pragma unroll
        for (int r = 0; r < 4; ++r) {
            const int d_l = i * 16 + q * 4 + r;
            const float bb = bias[d0 + wd + d_l];
            #pragma unroll
            for (int j = 0; j < 4; ++j) {
                const int p_l = j * 16 + m16;
                *(__hip_bfloat16*)(wb + d_l * 144 + p_l * 2) =
                    __float2bfloat16(acc[i][j][r] + bb);
            }
        }

    __hip_bfloat16* outbuf = (proj == 0) ? Qw : ((proj == 1) ? Kw : Vw);
    const int b = n >> 4, f = n & 15;
    __hip_bfloat16* dst = outbuf + (((size_t)(b * CC + d0 + wd)) * FF + f) * PP + p0 + wp;
    #pragma unroll
    for (int k = 0; k < 8; ++k) {
        const int d_l = k * 8 + dl2;
        bf16x8 v = *(const bf16x8*)(wb + d_l * 144 + pl2 * 16);
        *(bf16x8*)(dst + (size_t)d_l * FF * PP + pl2 * 8) = v;
    }
}

// ---------------------------------------------------------------------------
// attn_out: per (b,d): 4 waves compute partial S=Q·K^T over 256-p chunks
// (MFMA), partials summed in LDS; softmax; then AV + gamma*out + x, reading
// Q/K/V (bf16, [b][d][f][p] layout: per-(b,d) 32KB contiguous) from the
// workspace, writing fp32 out (thread t owns p=4t..4t+3).
// ---------------------------------------------------------------------------
__global__ __launch_bounds__(256) void attn_out(
    const __hip_bfloat16* __restrict__ Qw, const __hip_bfloat16* __restrict__ Kw,
    const __hip_bfloat16* __restrict__ Vw,
    const float* __restrict__ x, const float* __restrict__ gamma,
    float* __restrict__ out)
{
    const int d = blockIdx.x, b = blockIdx.y;
    const int t = threadIdx.x, w = t >> 6, lane = t & 63;
    const int q = lane >> 4, m16 = lane & 15;
    __shared__ float Sp[4][16][17];
    __shared__ float As[16][17];

    // S partials: wave w covers p in [w*256, w*256+256); lane row f = m16
    // is a 2KB-strided row within a contiguous 32KB (b,d) block.
    {
        const size_t gbase = (((size_t)(b * CC + d)) * FF + m16) * PP + w * 256 + q * 8;
        f32x4 acc0 = {0.f, 0.f, 0.f, 0.f}, acc1 = {0.f, 0.f, 0.f, 0.f};
        #pragma unroll
        for (int pc = 0; pc < 256; pc += 64) {
            bf16x8 aq0 = *(const bf16x8*)(Qw + gbase + pc);
            bf16x8 bk0 = *(const bf16x8*)(Kw + gbase + pc);
            bf16x8 aq1 = *(const bf16x8*)(Qw + gbase + pc + 32);
            bf16x8 bk1 = *(const bf16x8*)(Kw + gbase + pc + 32);
            acc0 = __builtin_amdgcn_mfma_f32_16x16x32_bf16(aq0, bk0, acc0, 0, 0, 0);
            acc1 = __builtin_amdgcn_mfma_f32_16x16x32_bf16(aq1, bk1, acc1, 0, 0, 0);
        }
        #pragma unroll
        for (int r = 0; r < 4; ++r)
            Sp[w][q * 4 + r][m16] = acc0[r] + acc1[r];
    }
    __syncthreads();

    // softmax: thread t handles (f1,f2) = (t>>4, t&15); 16-lane shuffle reduce
    {
        const int f1 = t >> 4, f2 = t & 15;
        const float s = (Sp[0][f1][f2] + Sp[1][f1][f2] + Sp[2][f1][f2] + Sp[3][f1][f2]) * 0.0625f;
        float m = s;
        #pragma unroll
        for (int off = 1; off < 16; off <<= 1) m = fmaxf(m, __shfl_xor(m, off));
        const float e = __expf(s - m);
        float den = e;
        #pragma unroll
        for (int off = 1; off < 16; off <<= 1) den += __shfl_xor(den, off);
        As[f1][f2] = e / den;
    }
    __syncthreads();

    // AV + epilogue: thread t owns p = 4t..4t+3 (V bf16 from workspace)
    const float g = gamma[0];
    const size_t base = ((size_t)(b * CC + d) * FF) * PP + t * 4;
    const __hip_bfloat16* Vb = Vw + base;
    f32x4 vv[16];
    #pragma unroll
    for (int f2 = 0; f2 < 16; ++f2) {
        const ushort4 rv = *(const ushort4*)(Vb + (size_t)f2 * PP);
        vv[f2] = (f32x4){ bf2f(rv.x), bf2f(rv.y), bf2f(rv.z), bf2f(rv.w) };
    }
    #pragma unroll
    for (int f1 = 0; f1 < 16; ++f1) {
        f32x4 a = {0.f, 0.f, 0.f, 0.f};
        #pragma unroll
        for (int f2 = 0; f2 < 16; ++f2) {
            const float av = As[f1][f2];
            a += av * vv[f2];
        }
        const f32x4 xv = *(const f32x4*)(x + base + (size_t)f1 * PP);
        const f32x4 res = g * a + xv;
        *(f32x4*)(out + base + (size_t)f1 * PP) = res;
    }
}

extern "C" void kernel_launch(void* const* d_in, const int* in_sizes, int n_in,
                              void* d_out, int out_size, void* d_ws, size_t ws_size,
                              hipStream_t stream) {
    const float* x     = (const float*)d_in[0];
    const float* wq    = (const float*)d_in[1];
    const float* bq    = (const float*)d_in[2];
    const float* wk    = (const float*)d_in[3];
    const float* bk    = (const float*)d_in[4];
    const float* wv    = (const float*)d_in[5];
    const float* bv    = (const float*)d_in[6];
    const float* gamma = (const float*)d_in[7];
    float* out = (float*)d_out;

    __hip_bfloat16* Qw = (__hip_bfloat16*)d_ws;                  // 32 MiB
    __hip_bfloat16* Kw = Qw + (size_t)NN * CC * PP;              // 32 MiB
    __hip_bfloat16* Vw = Kw + (size_t)NN * CC * PP;              // 32 MiB
    __hip_bfloat16* Wb = Vw + (size_t)NN * CC * PP;              // 384 KiB

    wconv_kernel<<<dim3(CC * CC / (256 * 4)), 256, 0, stream>>>(wq, wk, wv, Wb);
    qkv_fused<<<dim3(PP / 128, CC / 128, NN * 3), 256, 0, stream>>>(
        Wb, x, bq, bk, bv, Qw, Kw, Vw);
    attn_out<<<dim3(CC, BB), 256, 0, stream>>>(Qw, Kw, Vw, x, gamma, out);
}

// Round 10
// 192.058 us; speedup vs baseline: 1.1269x; 1.1269x over previous
//
#include <hip/hip_runtime.h>
#include <hip/hip_bf16.h>

// Problem dims (hard-coded): B=4, C=256, F=16, H=32, W=32 (fp32 in/out)
#define CC 256
#define FF 16
#define PP 1024
#define BB 4
#define NN 64   // B*F

typedef __bf16 bf16x8 __attribute__((ext_vector_type(8)));
typedef float  f32x4  __attribute__((ext_vector_type(4)));

// async 16B global -> LDS (per-lane global addr; LDS dest = wave-uniform base + lane*16)
__device__ __forceinline__ void async16(const __hip_bfloat16* g, char* l) {
    __builtin_amdgcn_global_load_lds(
        (const __attribute__((address_space(1))) unsigned int*)g,
        (__attribute__((address_space(3))) unsigned int*)l, 16, 0, 0);
}

__device__ __forceinline__ float bf2f(unsigned short u) {
    union { unsigned i; float f; } v; v.i = ((unsigned)u) << 16; return v.f;
}

// ---------------------------------------------------------------------------
// xt_kernel: Xt[n][p][c] (bf16) = x[n][c][p] (fp32).  64x64 LDS tile transpose.
// Extra gridDim.z slice (n == NN) converts wq/wk/wv fp32 -> Wb bf16.
// ---------------------------------------------------------------------------
__global__ __launch_bounds__(256) void xt_kernel(
    const float* __restrict__ x,
    const float* __restrict__ wq, const float* __restrict__ wk,
    const float* __restrict__ wv,
    __hip_bfloat16* __restrict__ Xt, __hip_bfloat16* __restrict__ Wb)
{
    __shared__ float T[64][65];
    const int n = blockIdx.z;
    const int t = threadIdx.x;

    if (n == NN) {   // weight-conversion slice: 64 blocks, 1 float4/thread/proj
        const int blk = blockIdx.y * 16 + blockIdx.x;   // 0..63
        const int idx = (blk * 256 + t) * 4;
        #pragma unroll
        for (int proj = 0; proj < 3; ++proj) {
            const float* src = proj == 0 ? wq : (proj == 1 ? wk : wv);
            __hip_bfloat16* dst = Wb + (size_t)proj * CC * CC;
            const float4 v = *(const float4*)(src + idx);
            __hip_bfloat162 h0, h1;
            h0.x = __float2bfloat16(v.x); h0.y = __float2bfloat16(v.y);
            h1.x = __float2bfloat16(v.z); h1.y = __float2bfloat16(v.w);
            *(__hip_bfloat162*)(dst + idx)     = h0;
            *(__hip_bfloat162*)(dst + idx + 2) = h1;
        }
        return;
    }

    const int c0 = blockIdx.y * 64, p0 = blockIdx.x * 64;
    const int pl = t & 63, r0 = t >> 6;          // load: lane along p
    const float* xp = x + ((size_t)n * CC + c0) * PP + p0;
    #pragma unroll
    for (int i = 0; i < 16; ++i) {
        const int cl = r0 + i * 4;
        T[cl][pl] = xp[(size_t)cl * PP + pl];
    }
    __syncthreads();
    __hip_bfloat16* op = Xt + ((size_t)n * PP + p0) * CC + c0;
    const int cl2 = (t & 31) * 2, q0 = t >> 5;   // store: lane covers 2 c's
    #pragma unroll
    for (int j = 0; j < 8; ++j) {
        const int pr = q0 + j * 8;
        __hip_bfloat162 h;
        h.x = __float2bfloat16(T[cl2][pr]);
        h.y = __float2bfloat16(T[cl2 + 1][pr]);
        *(__hip_bfloat162*)(op + (size_t)pr * CC + cl2) = h;
    }
}

// ---------------------------------------------------------------------------
// qkv_mfma: per (n,proj): Y[d][p] = sum_c W[d][c]*X[c][p] + bias[d]
// 128d x 128p tile, BK=64, LDS staging via global_load_lds(16B) with XOR
// granule swizzle (gc = col ^ (row&7)).  Epilogue bounces acc through a
// per-wave padded LDS tile (stride 144B) to emit coalesced 16B stores.
// ALL outputs use the [b][d][f][p] layout.
// XCD-aware bijective block swizzle: each XCD gets 24 contiguous z-slices
// (all 16 tiles of a slice share that XCD's L2 copy of Xt[n] / Wb[proj]).
// ---------------------------------------------------------------------------
__global__ __launch_bounds__(256) void qkv_mfma(
    const __hip_bfloat16* __restrict__ Wb, const __hip_bfloat16* __restrict__ Xt,
    const float* __restrict__ bq, const float* __restrict__ bk,
    const float* __restrict__ bv,
    __hip_bfloat16* __restrict__ Qw, __hip_bfloat16* __restrict__ Kw,
    __hip_bfloat16* __restrict__ Vw)
{
    __shared__ char lds[36864];   // staging: A 16K + B 16K; bounce: 4 x 9216

    // ---- XCD swizzle: lid = dispatch-linear id; wid = chunked remap ----
    const int lid = ((int)blockIdx.z * 2 + (int)blockIdx.y) * 8 + (int)blockIdx.x;
    const int wid = (lid & 7) * 384 + (lid >> 3);      // 3072 % 8 == 0: bijective
    const int p0 = (wid & 7) * 128;
    const int d0 = ((wid >> 3) & 1) * 128;
    const int z  = wid >> 4;
    const int proj = z % 3, n = z / 3;

    const int t = threadIdx.x, w = t >> 6, lane = t & 63;
    const int wd = (w >> 1) * 64, wp = (w & 1) * 64;
    const int q = lane >> 4, m16 = lane & 15;

    const __hip_bfloat16* Abase = Wb + (size_t)proj * CC * CC + (size_t)d0 * CC;
    const __hip_bfloat16* Bbase = Xt + (size_t)n * PP * CC + (size_t)p0 * CC;

    f32x4 acc[4][4];
    #pragma unroll
    for (int i = 0; i < 4; ++i)
        #pragma unroll
        for (int j = 0; j < 4; ++j)
            acc[i][j] = (f32x4){0.f, 0.f, 0.f, 0.f};

    for (int c0 = 0; c0 < CC; c0 += 64) {
        // stage: tile rows 0..127, 8 granules of 16B per row; slot s = t + 256k
        #pragma unroll
        for (int k = 0; k < 4; ++k) {
            const int s = t + 256 * k;
            const int row = s >> 3;
            const int gc = (s & 7) ^ (row & 7);
            async16(Abase + (size_t)row * CC + c0 + gc * 8, lds + s * 16);
            async16(Bbase + (size_t)row * CC + c0 + gc * 8, lds + 16384 + s * 16);
        }
        __syncthreads();
        #pragma unroll
        for (int kk = 0; kk < 2; ++kk) {
            bf16x8 a[4], b[4];
            #pragma unroll
            for (int i = 0; i < 4; ++i) {
                const int row = wd + i * 16 + m16;
                const int col = (4 * kk + q) ^ (row & 7);
                a[i] = *(const bf16x8*)(lds + row * 128 + col * 16);
            }
            #pragma unroll
            for (int j = 0; j < 4; ++j) {
                const int row = wp + j * 16 + m16;
                const int col = (4 * kk + q) ^ (row & 7);
                b[j] = *(const bf16x8*)(lds + 16384 + row * 128 + col * 16);
            }
            #pragma unroll
            for (int i = 0; i < 4; ++i)
                #pragma unroll
                for (int j = 0; j < 4; ++j)
                    acc[i][j] = __builtin_amdgcn_mfma_f32_16x16x32_bf16(a[i], b[j], acc[i][j], 0, 0, 0);
        }
        __syncthreads();
    }

    // ---- epilogue: bounce through per-wave LDS tile, emit coalesced stores ----
    __syncthreads();                       // all frag reads of staging done
    char* wb = lds + w * 9216;             // 64 rows x 144 B
    const int dl2 = lane >> 3, pl2 = lane & 7;

    const float* bias = (proj == 0) ? bq : ((proj == 1) ? bk : bv);
    #pragma unroll
    for (int i = 0; i < 4; ++i)
        #pragma unroll
        for (int r = 0; r < 4; ++r) {
            const int d_l = i * 16 + q * 4 + r;
            const float bb = bias[d0 + wd + d_l];
            #pragma unroll
            for (int j = 0; j < 4; ++j) {
                const int p_l = j * 16 + m16;
                *(__hip_bfloat16*)(wb + d_l * 144 + p_l * 2) =
                    __float2bfloat16(acc[i][j][r] + bb);
            }
        }

    __hip_bfloat16* outbuf = (proj == 0) ? Qw : ((proj == 1) ? Kw : Vw);
    const int b = n >> 4, f = n & 15;
    __hip_bfloat16* dst = outbuf + (((size_t)(b * CC + d0 + wd)) * FF + f) * PP + p0 + wp;
    #pragma unroll
    for (int k = 0; k < 8; ++k) {
        const int d_l = k * 8 + dl2;
        bf16x8 v = *(const bf16x8*)(wb + d_l * 144 + pl2 * 16);
        *(bf16x8*)(dst + (size_t)d_l * FF * PP + pl2 * 8) = v;
    }
}

// ---------------------------------------------------------------------------
// attn_out: per (b,d): 4 waves compute partial S=Q·K^T over 256-p chunks
// (MFMA), partials summed in LDS; softmax; then AV + gamma*out + x, reading
// Q/K/V (bf16, [b][d][f][p] layout: per-(b,d) 32KB contiguous) from the
// workspace, writing fp32 out (thread t owns p=4t..4t+3).
// ---------------------------------------------------------------------------
__global__ __launch_bounds__(256) void attn_out(
    const __hip_bfloat16* __restrict__ Qw, const __hip_bfloat16* __restrict__ Kw,
    const __hip_bfloat16* __restrict__ Vw,
    const float* __restrict__ x, const float* __restrict__ gamma,
    float* __restrict__ out)
{
    const int d = blockIdx.x, b = blockIdx.y;
    const int t = threadIdx.x, w = t >> 6, lane = t & 63;
    const int q = lane >> 4, m16 = lane & 15;
    __shared__ float Sp[4][16][17];
    __shared__ float As[16][17];

    // S partials: wave w covers p in [w*256, w*256+256); lane row f = m16
    // is a 2KB-strided row within a contiguous 32KB (b,d) block.
    {
        const size_t gbase = (((size_t)(b * CC + d)) * FF + m16) * PP + w * 256 + q * 8;
        f32x4 acc0 = {0.f, 0.f, 0.f, 0.f}, acc1 = {0.f, 0.f, 0.f, 0.f};
        #pragma unroll
        for (int pc = 0; pc < 256; pc += 64) {
            bf16x8 aq0 = *(const bf16x8*)(Qw + gbase + pc);
            bf16x8 bk0 = *(const bf16x8*)(Kw + gbase + pc);
            bf16x8 aq1 = *(const bf16x8*)(Qw + gbase + pc + 32);
            bf16x8 bk1 = *(const bf16x8*)(Kw + gbase + pc + 32);
            acc0 = __builtin_amdgcn_mfma_f32_16x16x32_bf16(aq0, bk0, acc0, 0, 0, 0);
            acc1 = __builtin_amdgcn_mfma_f32_16x16x32_bf16(aq1, bk1, acc1, 0, 0, 0);
        }
        #pragma unroll
        for (int r = 0; r < 4; ++r)
            Sp[w][q * 4 + r][m16] = acc0[r] + acc1[r];
    }
    __syncthreads();

    // softmax: thread t handles (f1,f2) = (t>>4, t&15); 16-lane shuffle reduce
    {
        const int f1 = t >> 4, f2 = t & 15;
        const float s = (Sp[0][f1][f2] + Sp[1][f1][f2] + Sp[2][f1][f2] + Sp[3][f1][f2]) * 0.0625f;
        float m = s;
        #pragma unroll
        for (int off = 1; off < 16; off <<= 1) m = fmaxf(m, __shfl_xor(m, off));
        const float e = __expf(s - m);
        float den = e;
        #pragma unroll
        for (int off = 1; off < 16; off <<= 1) den += __shfl_xor(den, off);
        As[f1][f2] = e / den;
    }
    __syncthreads();

    // AV + epilogue: thread t owns p = 4t..4t+3 (V bf16 from workspace)
    const float g = gamma[0];
    const size_t base = ((size_t)(b * CC + d) * FF) * PP + t * 4;
    const __hip_bfloat16* Vb = Vw + base;
    f32x4 vv[16];
    #pragma unroll
    for (int f2 = 0; f2 < 16; ++f2) {
        const ushort4 rv = *(const ushort4*)(Vb + (size_t)f2 * PP);
        vv[f2] = (f32x4){ bf2f(rv.x), bf2f(rv.y), bf2f(rv.z), bf2f(rv.w) };
    }
    #pragma unroll
    for (int f1 = 0; f1 < 16; ++f1) {
        f32x4 a = {0.f, 0.f, 0.f, 0.f};
        #pragma unroll
        for (int f2 = 0; f2 < 16; ++f2) {
            const float av = As[f1][f2];
            a += av * vv[f2];
        }
        const f32x4 xv = *(const f32x4*)(x + base + (size_t)f1 * PP);
        const f32x4 res = g * a + xv;
        *(f32x4*)(out + base + (size_t)f1 * PP) = res;
    }
}

extern "C" void kernel_launch(void* const* d_in, const int* in_sizes, int n_in,
                              void* d_out, int out_size, void* d_ws, size_t ws_size,
                              hipStream_t stream) {
    const float* x     = (const float*)d_in[0];
    const float* wq    = (const float*)d_in[1];
    const float* bq    = (const float*)d_in[2];
    const float* wk    = (const float*)d_in[3];
    const float* bk    = (const float*)d_in[4];
    const float* wv    = (const float*)d_in[5];
    const float* bv    = (const float*)d_in[6];
    const float* gamma = (const float*)d_in[7];
    float* out = (float*)d_out;

    __hip_bfloat16* Qw = (__hip_bfloat16*)d_ws;                  // 32 MiB
    __hip_bfloat16* Kw = Qw + (size_t)NN * CC * PP;              // 32 MiB
    __hip_bfloat16* Vw = Kw + (size_t)NN * CC * PP;              // 32 MiB
    __hip_bfloat16* Wb = Vw + (size_t)NN * CC * PP;              // 384 KiB
    __hip_bfloat16* Xt = (__hip_bfloat16*)d_out;                 // Xt lives in out
                                                                 // (dead before attn_out writes)

    xt_kernel<<<dim3(PP / 64, CC / 64, NN + 1), 256, 0, stream>>>(
        x, wq, wk, wv, Xt, Wb);
    qkv_mfma<<<dim3(PP / 128, CC / 128, NN * 3), 256, 0, stream>>>(
        Wb, Xt, bq, bk, bv, Qw, Kw, Vw);
    attn_out<<<dim3(CC, BB), 256, 0, stream>>>(Qw, Kw, Vw, x, gamma, out);
}